// Round 3
// baseline (118.636 us; speedup 1.0000x reference)
//
#include <hip/hip_runtime.h>
#include <hip/hip_bf16.h>

// Problem constants
#define Bc 2
#define Nc 6
#define Cc 64
#define Hc 28
#define Wc 50
#define Dc 59
#define BHc 200
#define BWc 200
// BEV_X0 = BEV_Y0 = -50.0, RES = 0.5

#define DSPLIT 2          // blocks per (b,n,w) along d
#define DCHUNK 32         // d's per block
#define DWAVE 8           // d's per wave (4 waves x 8 = 32)

// One block per (b,n,w,dhalf). lane = channel c.
// Phase 1 (per wave, its 8 d's): lane h computes the exact reference f32
//   chain, ballot validity, prim bin; stores masked depth into mdep (XOR-
//   swizzled); rare non-matching h handled by per-h fallback atomic.
// Phase 2: fixed-trip dense matmul over h: accv[d] += feat[h][c]*mdep[h][d]
//   (b128 broadcast reads, fully unrolled, no serial latency chain).
// Phase 3: one 64-lane atomic per (d).
__global__ __launch_bounds__(256) void fp_scatter3(
    const float* __restrict__ feats,   // (B,N,C,H,W)
    const float* __restrict__ depth,   // (B,N,D,H,W)
    const float* __restrict__ Kmat,    // (B,N,3,3)
    const float* __restrict__ Emat,    // (B,N,4,4)
    float* __restrict__ acc)           // (B, BH*BW, C)
{
    __shared__ __align__(16) float feat_lds[Hc][Cc];   // [h][c]
    // mdep[h][ld], ld = local d in [0,32), stored XOR-swizzled:
    //   element (h, ld) lives at byte  h*128 + ((ld*4) ^ ((h&7)<<4))
    // i.e. 16B-block index (ld>>2) ^ (h&7), low 2 bits (ld&3) unpermuted.
    __shared__ __align__(16) float mdep[Hc][DCHUNK];

    int blk   = blockIdx.x;
    int dhalf = blk & 1;
    int pix   = blk >> 1;                // (b*N + n)*W + w
    int w  = pix % Wc;
    int bn = pix / Wc;
    int b  = bn / Nc;
    int tid  = threadIdx.x;
    int lane = tid & 63;
    int wid  = tid >> 6;

    const size_t HW = (size_t)Hc * Wc;
    const float* fbase = feats + (size_t)bn * Cc * HW + w;
    const float* dbase = depth + (size_t)bn * Dc * HW + w;

    // Stage feat column: feat_lds[h][c] = feats[b,n,c,h,w]
    for (int h = wid; h < Hc; h += 4)
        feat_lds[h][lane] = fbase[(size_t)lane * HW + (size_t)h * Wc];

    // ---- K inverse (f32 adjugate, correctly-rounded division) ----
    const float* K = Kmat + (size_t)bn * 9;
    float k00 = K[0], k01 = K[1], k02 = K[2];
    float k10 = K[3], k11 = K[4], k12 = K[5];
    float k20 = K[6], k21 = K[7], k22 = K[8];

    float c00 = __fsub_rn(__fmul_rn(k11, k22), __fmul_rn(k12, k21));
    float c01 = __fsub_rn(__fmul_rn(k12, k20), __fmul_rn(k10, k22));
    float c02 = __fsub_rn(__fmul_rn(k10, k21), __fmul_rn(k11, k20));
    float det = __fadd_rn(__fadd_rn(__fmul_rn(k00, c00), __fmul_rn(k01, c01)),
                          __fmul_rn(k02, c02));
    float i00 = __fdiv_rn(c00, det);
    float i01 = __fdiv_rn(__fsub_rn(__fmul_rn(k02, k21), __fmul_rn(k01, k22)), det);
    float i02 = __fdiv_rn(__fsub_rn(__fmul_rn(k01, k12), __fmul_rn(k02, k11)), det);
    float i10 = __fdiv_rn(c01, det);
    float i11 = __fdiv_rn(__fsub_rn(__fmul_rn(k00, k22), __fmul_rn(k02, k20)), det);
    float i12 = __fdiv_rn(__fsub_rn(__fmul_rn(k02, k10), __fmul_rn(k00, k12)), det);
    float i20 = __fdiv_rn(c02, det);
    float i21 = __fdiv_rn(__fsub_rn(__fmul_rn(k01, k20), __fmul_rn(k00, k21)), det);
    float i22 = __fdiv_rn(__fsub_rn(__fmul_rn(k00, k11), __fmul_rn(k01, k10)), det);

    const float* E = Emat + (size_t)bn * 16;
    float r00 = E[0], r01 = E[1], r02 = E[2],  tx = E[3];
    float r10 = E[4], r11 = E[5], r12 = E[6],  ty = E[7];
    float r20 = E[8], r21 = E[9], r22 = E[10], tz = E[11];

    __syncthreads();   // feat_lds ready (mdep is same-wave produce/consume)

    float* accb = acc + (size_t)b * (BHc * BWc) * Cc;

    int h = lane;                        // geometry lane role
    float xf = (float)w;
    float yf = (float)h;
    int ld0 = wid * DWAVE;               // this wave's local-d window

    float accv[DWAVE];
    int   prim[DWAVE];

    // ---- Phase 1: geometry + masked-depth store ----
#pragma unroll
    for (int k = 0; k < DWAVE; ++k) {
        accv[k] = 0.0f;
        prim[k] = -1;
        int ld = ld0 + k;
        int dg = dhalf * DCHUNK + ld;
        if (dg < Dc) {
            float db = (float)(dg + 1);          // depth bins 1..59
            float dep = 0.0f;
            if (h < Hc) dep = dbase[(size_t)dg * HW + (size_t)h * Wc];

            float px = __fmul_rn(xf, db);
            float py = __fmul_rn(yf, db);
            float pz = db;

            float cx = __fadd_rn(__fadd_rn(__fmul_rn(i00, px), __fmul_rn(i01, py)), __fmul_rn(i02, pz));
            float cy = __fadd_rn(__fadd_rn(__fmul_rn(i10, px), __fmul_rn(i11, py)), __fmul_rn(i12, pz));
            float cz = __fadd_rn(__fadd_rn(__fmul_rn(i20, px), __fmul_rn(i21, py)), __fmul_rn(i22, pz));

            float ex = __fadd_rn(__fadd_rn(__fadd_rn(__fmul_rn(r00, cx), __fmul_rn(r01, cy)), __fmul_rn(r02, cz)), tx);
            float ey = __fadd_rn(__fadd_rn(__fadd_rn(__fmul_rn(r10, cx), __fmul_rn(r11, cy)), __fmul_rn(r12, cz)), ty);
            float ez = __fadd_rn(__fadd_rn(__fadd_rn(__fmul_rn(r20, cx), __fmul_rn(r21, cy)), __fmul_rn(r22, cz)), tz);

            int bx = (int)(__fmul_rn(__fadd_rn(ex, 50.0f), 2.0f));
            int by = (int)(__fmul_rn(__fadd_rn(ey, 50.0f), 2.0f));

            bool valid = (h < Hc) & (bx >= 0) & (bx < BWc) & (by >= 0) & (by < BHc) & (ez > 0.0f);
            int binidx = by * BWc + bx;

            unsigned long long vm = __ballot(valid);
            float val = 0.0f;
            if (vm != 0ULL) {
                int first = __builtin_ctzll(vm);
                int pr = __shfl(binidx, first);
                unsigned long long match = __ballot(valid && (binidx == pr));
                unsigned long long rest  = vm & ~match;
                prim[k] = pr;
                val = (valid && (binidx == pr)) ? dep : 0.0f;

                // fallback: valid h with a different bin (general case)
                while (rest) {
                    int hh2 = __builtin_ctzll(rest);
                    rest &= rest - 1;
                    int   bidx = __shfl(binidx, hh2);
                    float dv   = __shfl(dep, hh2);
                    atomicAdd(&accb[(size_t)bidx * Cc + lane],
                              __fmul_rn(feat_lds[hh2][lane], dv));
                }
            }
            if (h < Hc) {
                // swizzled store of element (h, ld)
                char* base = (char*)&mdep[h][0];
                *(float*)(base + (((ld << 2) ^ ((h & 7) << 4)))) = val;
            }
        }
    }

    // ---- Phase 2: dense masked matmul over h (same-wave mdep) ----
    int lb0 = ld0 >> 2;                  // first logical 16B-block
#pragma unroll
    for (int hh = 0; hh < Hc; ++hh) {
        float f = feat_lds[hh][lane];
        const float4* rowp = (const float4*)&mdep[hh][0];
        float4 v0 = rowp[(lb0 + 0) ^ (hh & 7)];   // ld0..ld0+3
        float4 v1 = rowp[(lb0 + 1) ^ (hh & 7)];   // ld0+4..ld0+7
        accv[0] = __builtin_fmaf(f, v0.x, accv[0]);
        accv[1] = __builtin_fmaf(f, v0.y, accv[1]);
        accv[2] = __builtin_fmaf(f, v0.z, accv[2]);
        accv[3] = __builtin_fmaf(f, v0.w, accv[3]);
        accv[4] = __builtin_fmaf(f, v1.x, accv[4]);
        accv[5] = __builtin_fmaf(f, v1.y, accv[5]);
        accv[6] = __builtin_fmaf(f, v1.z, accv[6]);
        accv[7] = __builtin_fmaf(f, v1.w, accv[7]);
    }

    // ---- Phase 3: one 64-lane atomic per d ----
#pragma unroll
    for (int k = 0; k < DWAVE; ++k) {
        if (prim[k] >= 0)
            atomicAdd(&accb[(size_t)prim[k] * Cc + lane], accv[k]);
    }
}

// (B, BH*BW, C) -> (B, C, BH*BW), LDS-tiled 64x64
__global__ __launch_bounds__(256) void fp_transpose_kernel(
    const float* __restrict__ acc, float* __restrict__ out)
{
    __shared__ float tile[64][65];
    const int P = BHc * BWc;                 // 40000, divisible by 64
    int b = blockIdx.y;
    int p0 = blockIdx.x * 64;
    int tx = threadIdx.x & 63;
    int ty = threadIdx.x >> 6;               // 0..3

    const float* src = acc + (size_t)b * P * Cc;
#pragma unroll
    for (int i = 0; i < 16; ++i) {
        int row = ty * 16 + i;
        tile[row][tx] = src[(size_t)(p0 + row) * Cc + tx];
    }
    __syncthreads();
    float* dst = out + (size_t)b * Cc * P;
#pragma unroll
    for (int i = 0; i < 16; ++i) {
        int c = ty * 16 + i;
        dst[(size_t)c * P + p0 + tx] = tile[tx][c];
    }
}

extern "C" void kernel_launch(void* const* d_in, const int* in_sizes, int n_in,
                              void* d_out, int out_size, void* d_ws, size_t ws_size,
                              hipStream_t stream) {
    const float* feats = (const float*)d_in[0];
    const float* depth = (const float*)d_in[1];
    const float* Kmat  = (const float*)d_in[2];
    const float* Emat  = (const float*)d_in[3];
    float* out = (float*)d_out;

    const size_t ACC_ELEMS = (size_t)Bc * BHc * BWc * Cc;   // 5,120,000
    const size_t ACC_BYTES = ACC_ELEMS * sizeof(float);     // 20.48 MB
    float* acc = (float*)d_ws;

    hipMemsetAsync(acc, 0, ACC_BYTES, stream);

    const int NBLK = Bc * Nc * Wc * DSPLIT;  // 1200 blocks
    fp_scatter3<<<NBLK, 256, 0, stream>>>(feats, depth, Kmat, Emat, acc);

    fp_transpose_kernel<<<dim3((BHc * BWc) / 64, Bc), 256, 0, stream>>>(acc, out);
}

// Round 4
// 111.883 us; speedup vs baseline: 1.0604x; 1.0604x over previous
//
#include <hip/hip_runtime.h>
#include <hip/hip_bf16.h>

// Problem constants
#define Bc 2
#define Nc 6
#define Cc 64
#define Hc 28
#define Wc 50
#define Dc 59
#define BHc 200
#define BWc 200
// BEV_X0 = BEV_Y0 = -50.0, RES = 0.5

#define DSPLIT 4          // blocks per (b,n,w) along d
#define DCHUNK 16         // d slots per block (4*16=64 >= 59, guarded)
#define DWAVE 4           // d's per wave (4 waves x 4 = 16)

#define HWc (Hc * Wc)     // 1400
#define NT1 (Bc * Nc * 22)       // feat tiles: ceil(1400/64)=22 per (b,n)
#define NT2 (Bc * Nc * Dc)       // depth planes

// ---------------------------------------------------------------------------
// Pre-transpose: feats (B,N,C,H,W) -> F' (B,N,H,W,C)
//                depth (B,N,D,H,W) -> D'' (B,N,D,W,H)
// Both sides coalesced via LDS tiles.
__global__ __launch_bounds__(256) void fp_pretrans(
    const float* __restrict__ feats,
    const float* __restrict__ depth,
    float* __restrict__ Fp,            // (B,N,H,W,C)
    float* __restrict__ Dpp)           // (B,N,D,W,H)
{
    __shared__ float t[64][65];
    __shared__ float t2[Hc][Wc + 1];

    int bid = blockIdx.x;
    int tid = threadIdx.x;

    if (bid < NT1) {
        // feat tile: (c, hw) -> (hw, c), 64 x 64 tile
        int bn  = bid / 22;
        int hw0 = (bid % 22) * 64;
        int tx = tid & 63;
        int ty = tid >> 6;
        const float* src = feats + (size_t)bn * Cc * HWc;
        float* dst = Fp + (size_t)bn * HWc * Cc;
#pragma unroll
        for (int i = 0; i < 16; ++i) {
            int c = ty * 16 + i;
            int hw = hw0 + tx;
            t[c][tx] = (hw < HWc) ? src[(size_t)c * HWc + hw] : 0.0f;
        }
        __syncthreads();
#pragma unroll
        for (int i = 0; i < 16; ++i) {
            int j = ty * 16 + i;                 // hw-local
            if (hw0 + j < HWc)
                dst[(size_t)(hw0 + j) * Cc + tx] = t[tx][j];
        }
    } else {
        // depth plane: (h,w) -> (w,h) within plane (b,n,d)
        int bid2 = bid - NT1;
        int bn = bid2 / Dc;
        int d  = bid2 % Dc;
        const float* sp = depth + ((size_t)bn * Dc + d) * HWc;
        float* dp = Dpp + ((size_t)bn * Dc + d) * HWc;
        for (int idx = tid; idx < HWc; idx += 256)
            t2[idx / Wc][idx % Wc] = sp[idx];
        __syncthreads();
        for (int idx = tid; idx < HWc; idx += 256) {
            int w = idx / Hc, h = idx % Hc;
            dp[idx] = t2[h][w];
        }
    }
}

// ---------------------------------------------------------------------------
// Scatter v4: block per (b,n,w,dq). lane = channel c.
// Phase 0: stage feat column (28x64) from F' (coalesced 256B rows).
// Phase 1: lane h computes exact reference f32 chain for its 4 d's; ballot,
//   prim bin, masked depth -> swizzled LDS; rare mismatch h -> fallback atomic.
// Phase 2: dense masked matmul accv[k] += feat[h][c] * mdep[h][d].
// Phase 3: one 64-lane atomic per d.
__global__ __launch_bounds__(256) void fp_scatter4(
    const float* __restrict__ Fp,      // (B,N,H,W,C)
    const float* __restrict__ Dpp,     // (B,N,D,W,H)
    const float* __restrict__ Kmat,    // (B,N,3,3)
    const float* __restrict__ Emat,    // (B,N,4,4)
    float* __restrict__ acc)           // (B, BH*BW, C)
{
    __shared__ __align__(16) float feat_lds[Hc][Cc];   // [h][c]
    // mdep[h][slot]: element (h, ld) at float index ld ^ ((h&3)<<2);
    // row stride 20 floats (80B, 16B-aligned; slot 4 is pad).
    __shared__ __align__(16) float mdep[Hc][20];

    int bid = blockIdx.x;
    int dq  = bid & (DSPLIT - 1);
    int pix = bid >> 2;                  // (b*N + n)*W + w
    int w  = pix % Wc;
    int bn = pix / Wc;
    int b  = bn / Nc;
    int tid  = threadIdx.x;
    int lane = tid & 63;
    int wid  = tid >> 6;

    // Phase 0: stage feat column, coalesced
    const float* fbase = Fp + ((size_t)bn * Hc * Wc + w) * Cc;
    for (int hh = wid; hh < Hc; hh += 4)
        feat_lds[hh][lane] = fbase[(size_t)hh * Wc * Cc + lane];

    // ---- K inverse (f32 adjugate, correctly-rounded division) ----
    const float* K = Kmat + (size_t)bn * 9;
    float k00 = K[0], k01 = K[1], k02 = K[2];
    float k10 = K[3], k11 = K[4], k12 = K[5];
    float k20 = K[6], k21 = K[7], k22 = K[8];

    float c00 = __fsub_rn(__fmul_rn(k11, k22), __fmul_rn(k12, k21));
    float c01 = __fsub_rn(__fmul_rn(k12, k20), __fmul_rn(k10, k22));
    float c02 = __fsub_rn(__fmul_rn(k10, k21), __fmul_rn(k11, k20));
    float det = __fadd_rn(__fadd_rn(__fmul_rn(k00, c00), __fmul_rn(k01, c01)),
                          __fmul_rn(k02, c02));
    float i00 = __fdiv_rn(c00, det);
    float i01 = __fdiv_rn(__fsub_rn(__fmul_rn(k02, k21), __fmul_rn(k01, k22)), det);
    float i02 = __fdiv_rn(__fsub_rn(__fmul_rn(k01, k12), __fmul_rn(k02, k11)), det);
    float i10 = __fdiv_rn(c01, det);
    float i11 = __fdiv_rn(__fsub_rn(__fmul_rn(k00, k22), __fmul_rn(k02, k20)), det);
    float i12 = __fdiv_rn(__fsub_rn(__fmul_rn(k02, k10), __fmul_rn(k00, k12)), det);
    float i20 = __fdiv_rn(c02, det);
    float i21 = __fdiv_rn(__fsub_rn(__fmul_rn(k01, k20), __fmul_rn(k00, k21)), det);
    float i22 = __fdiv_rn(__fsub_rn(__fmul_rn(k00, k11), __fmul_rn(k01, k10)), det);

    const float* E = Emat + (size_t)bn * 16;
    float r00 = E[0], r01 = E[1], r02 = E[2],  tx = E[3];
    float r10 = E[4], r11 = E[5], r12 = E[6],  ty = E[7];
    float r20 = E[8], r21 = E[9], r22 = E[10], tz = E[11];

    __syncthreads();   // feat_lds ready (fallback may read any h)

    float* accb = acc + (size_t)b * (BHc * BWc) * Cc;

    int h = lane;                        // geometry lane role
    float xf = (float)w;
    float yf = (float)h;
    int ld0 = wid * DWAVE;

    float accv[DWAVE];
    int   prim[DWAVE];

    // ---- Phase 1: geometry + masked-depth store ----
#pragma unroll
    for (int k = 0; k < DWAVE; ++k) {
        accv[k] = 0.0f;
        prim[k] = -1;
        int ld = ld0 + k;
        int dg = dq * DCHUNK + ld;
        if (dg < Dc) {
            float db = (float)(dg + 1);          // depth bins 1..59
            float dep = 0.0f;
            if (h < Hc)
                dep = Dpp[(((size_t)bn * Dc + dg) * Wc + w) * Hc + h];

            float px = __fmul_rn(xf, db);
            float py = __fmul_rn(yf, db);
            float pz = db;

            float cx = __fadd_rn(__fadd_rn(__fmul_rn(i00, px), __fmul_rn(i01, py)), __fmul_rn(i02, pz));
            float cy = __fadd_rn(__fadd_rn(__fmul_rn(i10, px), __fmul_rn(i11, py)), __fmul_rn(i12, pz));
            float cz = __fadd_rn(__fadd_rn(__fmul_rn(i20, px), __fmul_rn(i21, py)), __fmul_rn(i22, pz));

            float ex = __fadd_rn(__fadd_rn(__fadd_rn(__fmul_rn(r00, cx), __fmul_rn(r01, cy)), __fmul_rn(r02, cz)), tx);
            float ey = __fadd_rn(__fadd_rn(__fadd_rn(__fmul_rn(r10, cx), __fmul_rn(r11, cy)), __fmul_rn(r12, cz)), ty);
            float ez = __fadd_rn(__fadd_rn(__fadd_rn(__fmul_rn(r20, cx), __fmul_rn(r21, cy)), __fmul_rn(r22, cz)), tz);

            int bx = (int)(__fmul_rn(__fadd_rn(ex, 50.0f), 2.0f));
            int by = (int)(__fmul_rn(__fadd_rn(ey, 50.0f), 2.0f));

            bool valid = (h < Hc) & (bx >= 0) & (bx < BWc) & (by >= 0) & (by < BHc) & (ez > 0.0f);
            int binidx = by * BWc + bx;

            unsigned long long vm = __ballot(valid);
            float val = 0.0f;
            if (vm != 0ULL) {
                int first = __builtin_ctzll(vm);
                int pr = __shfl(binidx, first);
                unsigned long long match = __ballot(valid && (binidx == pr));
                unsigned long long rest  = vm & ~match;
                prim[k] = pr;
                val = (valid && (binidx == pr)) ? dep : 0.0f;

                // fallback: valid h with a different bin (general case)
                while (rest) {
                    int hh2 = __builtin_ctzll(rest);
                    rest &= rest - 1;
                    int   bidx = __shfl(binidx, hh2);
                    float dv   = __shfl(dep, hh2);
                    atomicAdd(&accb[(size_t)bidx * Cc + lane],
                              __fmul_rn(feat_lds[hh2][lane], dv));
                }
            }
            if (h < Hc)
                mdep[h][ld ^ ((h & 3) << 2)] = val;   // swizzled store
        }
    }

    // ---- Phase 2: dense masked matmul over h (same-wave mdep) ----
#pragma unroll
    for (int hh = 0; hh < Hc; ++hh) {
        float f = feat_lds[hh][lane];
        const float4* rowp = (const float4*)&mdep[hh][0];
        float4 v0 = rowp[wid ^ (hh & 3)];     // lds ld0..ld0+3 in order
        accv[0] = __builtin_fmaf(f, v0.x, accv[0]);
        accv[1] = __builtin_fmaf(f, v0.y, accv[1]);
        accv[2] = __builtin_fmaf(f, v0.z, accv[2]);
        accv[3] = __builtin_fmaf(f, v0.w, accv[3]);
    }

    // ---- Phase 3: one 64-lane atomic per d ----
#pragma unroll
    for (int k = 0; k < DWAVE; ++k) {
        if (prim[k] >= 0)
            atomicAdd(&accb[(size_t)prim[k] * Cc + lane], accv[k]);
    }
}

// (B, BH*BW, C) -> (B, C, BH*BW), LDS-tiled 64x64
__global__ __launch_bounds__(256) void fp_transpose_kernel(
    const float* __restrict__ acc, float* __restrict__ out)
{
    __shared__ float tile[64][65];
    const int P = BHc * BWc;                 // 40000, divisible by 64
    int b = blockIdx.y;
    int p0 = blockIdx.x * 64;
    int tx = threadIdx.x & 63;
    int ty = threadIdx.x >> 6;               // 0..3

    const float* src = acc + (size_t)b * P * Cc;
#pragma unroll
    for (int i = 0; i < 16; ++i) {
        int row = ty * 16 + i;
        tile[row][tx] = src[(size_t)(p0 + row) * Cc + tx];
    }
    __syncthreads();
    float* dst = out + (size_t)b * Cc * P;
#pragma unroll
    for (int i = 0; i < 16; ++i) {
        int c = ty * 16 + i;
        dst[(size_t)c * P + p0 + tx] = tile[tx][c];
    }
}

extern "C" void kernel_launch(void* const* d_in, const int* in_sizes, int n_in,
                              void* d_out, int out_size, void* d_ws, size_t ws_size,
                              hipStream_t stream) {
    const float* feats = (const float*)d_in[0];
    const float* depth = (const float*)d_in[1];
    const float* Kmat  = (const float*)d_in[2];
    const float* Emat  = (const float*)d_in[3];
    float* out = (float*)d_out;

    const size_t ACC_ELEMS = (size_t)Bc * BHc * BWc * Cc;   // 5,120,000
    const size_t ACC_BYTES = ACC_ELEMS * sizeof(float);     // 20.48 MB
    const size_t F_ELEMS = (size_t)Bc * Nc * Hc * Wc * Cc;  // 1,075,200
    const size_t D_ELEMS = (size_t)Bc * Nc * Dc * Hc * Wc;  //   991,200

    float* acc = (float*)d_ws;
    float* Fp  = acc + ACC_ELEMS;
    float* Dpp = Fp + F_ELEMS;
    (void)D_ELEMS;

    hipMemsetAsync(acc, 0, ACC_BYTES, stream);

    fp_pretrans<<<NT1 + NT2, 256, 0, stream>>>(feats, depth, Fp, Dpp);

    const int NBLK = Bc * Nc * Wc * DSPLIT;  // 2400
    fp_scatter4<<<NBLK, 256, 0, stream>>>(Fp, Dpp, Kmat, Emat, acc);

    fp_transpose_kernel<<<dim3((BHc * BWc) / 64, Bc), 256, 0, stream>>>(acc, out);
}